// Round 3
// baseline (551.867 us; speedup 1.0000x reference)
//
#include <hip/hip_runtime.h>
#include <hip/hip_bf16.h>
#include <stdint.h>

#define B_  4
#define S_  2048
#define D_  1024
#define H_  16
#define HD_ 64

typedef __attribute__((ext_vector_type(4))) float f32x4;
typedef __attribute__((ext_vector_type(8))) short bf16x8;

typedef const unsigned int __attribute__((address_space(1)))* gas_ptr;
typedef unsigned int __attribute__((address_space(3)))* las_ptr;

__device__ __forceinline__ void async16(const void* g, void* l) {
  __builtin_amdgcn_global_load_lds((gas_ptr)g, (las_ptr)l, 16, 0, 0);
}

// ---------------------------------------------------------------------------
// Kernel A: x fp32 -> bf16, vectorized (n multiple of 4).
// ---------------------------------------------------------------------------
__global__ __launch_bounds__(256) void cvt_x(const float* __restrict__ in,
                                             __hip_bfloat16* __restrict__ out,
                                             int n) {
  const int i = (blockIdx.x * blockDim.x + threadIdx.x) * 4;
  if (i >= n) return;
  const float4 v = *(const float4*)(in + i);
  union { ushort4 u; __hip_bfloat16 h[4]; } o;
  o.h[0] = (__hip_bfloat16)v.x;
  o.h[1] = (__hip_bfloat16)v.y;
  o.h[2] = (__hip_bfloat16)v.z;
  o.h[3] = (__hip_bfloat16)v.w;
  *(ushort4*)(out + i) = o.u;
}

// ---------------------------------------------------------------------------
// Kernel 0: weights fp32 [K,N] -> bf16 transposed [N,K]; Wq/Wk/Wv concat into
// Wt_qkv [3072][1024], Wo -> Wt_o [1024][1024].
// ---------------------------------------------------------------------------
__global__ void transpose_w(const float* __restrict__ Wq,
                            const float* __restrict__ Wk,
                            const float* __restrict__ Wv,
                            const float* __restrict__ Wo,
                            __hip_bfloat16* __restrict__ Wt_qkv,
                            __hip_bfloat16* __restrict__ Wt_o) {
  __shared__ float t[32][33];
  const int z = blockIdx.z;
  const float* W = (z == 0) ? Wq : (z == 1) ? Wk : (z == 2) ? Wv : Wo;
  __hip_bfloat16* Wt = (z < 3) ? (Wt_qkv + (size_t)z * D_ * D_) : Wt_o;
  const int x = blockIdx.x * 32 + threadIdx.x;
  const int y = blockIdx.y * 32 + threadIdx.y;
  t[threadIdx.y][threadIdx.x] = W[(size_t)y * D_ + x];
  __syncthreads();
  const int xo = blockIdx.y * 32 + threadIdx.x;
  const int yo = blockIdx.x * 32 + threadIdx.y;
  Wt[(size_t)yo * D_ + xo] = (__hip_bfloat16)t[threadIdx.x][threadIdx.y];
}

// ---------------------------------------------------------------------------
// Kernel 1/3: C[M,N] = A[M,K] @ Bt[N,K]^T + bias (m97-style gemm_bt).
// 128x128 tile, BK=32, 4 waves of 64x64, global_load_lds width=16.
// bias fp32: cols [0,1024)->b0, [1024,2048)->b1, [2048,3072)->b2.
// OutT = __hip_bfloat16 (QKV) or float (final output).
// ---------------------------------------------------------------------------
template <typename OutT>
__global__ __launch_bounds__(256) void gemm_bt_bias(
    const __hip_bfloat16* __restrict__ A,
    const __hip_bfloat16* __restrict__ Bt,
    const float* __restrict__ b0,
    const float* __restrict__ b1,
    const float* __restrict__ b2,
    OutT* __restrict__ C,
    int M, int N, int K) {
  __shared__ __hip_bfloat16 sA[128 * 32];
  __shared__ __hip_bfloat16 sB[128 * 32];
  const int tid  = threadIdx.x;
  const int wave = tid >> 6;
  const int lane = tid & 63;
  const int quad = lane >> 4;
  const int l16  = lane & 15;
  const int bm = blockIdx.y * 128;
  const int bn = blockIdx.x * 128;
  const int wm = (wave >> 1) * 64;
  const int wn = (wave & 1) * 64;

  // staging: wave w covers rows [w*32, w*32+32) of each 128x32 tile
  const int r0 = wave * 2, r1 = wave * 2 + 1;   // 1KB regions (16 rows each)
  const int lrow = lane >> 2;                   // 0..15 row within region
  const int lcol = (lane & 3) * 8;              // bf16 elem offset (16B chunk)

  const __hip_bfloat16* ga0 = A  + (size_t)(bm + r0 * 16 + lrow) * K + lcol;
  const __hip_bfloat16* ga1 = A  + (size_t)(bm + r1 * 16 + lrow) * K + lcol;
  const __hip_bfloat16* gb0 = Bt + (size_t)(bn + r0 * 16 + lrow) * K + lcol;
  const __hip_bfloat16* gb1 = Bt + (size_t)(bn + r1 * 16 + lrow) * K + lcol;
  char* la0 = (char*)sA + r0 * 1024;
  char* la1 = (char*)sA + r1 * 1024;
  char* lb0 = (char*)sB + r0 * 1024;
  char* lb1 = (char*)sB + r1 * 1024;

  const char* pa = (const char*)sA + (wm + l16) * 64 + quad * 16;
  const char* pb = (const char*)sB + (wn + l16) * 64 + quad * 16;

  f32x4 acc[4][4] = {};

  for (int k0 = 0; k0 < K; k0 += 32) {
    async16(ga0 + k0, la0);
    async16(ga1 + k0, la1);
    async16(gb0 + k0, lb0);
    async16(gb1 + k0, lb1);
    __syncthreads();
    bf16x8 af[4], bf[4];
#pragma unroll
    for (int mt = 0; mt < 4; ++mt) af[mt] = *(const bf16x8*)(pa + mt * 1024);
#pragma unroll
    for (int nt = 0; nt < 4; ++nt) bf[nt] = *(const bf16x8*)(pb + nt * 1024);
#pragma unroll
    for (int mt = 0; mt < 4; ++mt)
#pragma unroll
      for (int nt = 0; nt < 4; ++nt)
        acc[mt][nt] = __builtin_amdgcn_mfma_f32_16x16x32_bf16(af[mt], bf[nt], acc[mt][nt], 0, 0, 0);
    __syncthreads();
  }

#pragma unroll
  for (int mt = 0; mt < 4; ++mt) {
    const int row = bm + wm + mt * 16 + quad * 4;  // C row = quad*4 + reg
#pragma unroll
    for (int nt = 0; nt < 4; ++nt) {
      const int col = bn + wn + nt * 16 + l16;     // C col = lane&15
      const float* bp = (col < 1024) ? b0 : ((col < 2048) ? b1 : b2);
      const float bias = bp[col & 1023];
      f32x4 v = acc[mt][nt];
#pragma unroll
      for (int r = 0; r < 4; ++r)
        C[(size_t)(row + r) * N + col] = (OutT)(v[r] + bias);
    }
  }
}

// ---------------------------------------------------------------------------
// Kernel 2: flash attention. QKV [B*S][3072] bf16 (Q|K|V each [.,1024],
// head h at cols h*64..h*64+63). mask [B][S][S] int32. O [B*S][1024] bf16.
// Block = 256 thr (4 waves), 64 Q-rows per block (16 per wave), K-tiles of 64.
// ---------------------------------------------------------------------------
__global__ __launch_bounds__(256) void flash_attn(
    const __hip_bfloat16* __restrict__ QKV,
    const int* __restrict__ mask,
    __hip_bfloat16* __restrict__ O) {
  __shared__ __hip_bfloat16 sQ[64 * 72];      // [qrow][hd], padded stride 72
  __shared__ __hip_bfloat16 sK[64 * 72];      // [kcol][hd]
  __shared__ __hip_bfloat16 sVt[64 * 72];     // [hd][kcol] (transposed)
  __shared__ __hip_bfloat16 sP[4][16 * 72];   // per-wave P round-trip

  const int qt = blockIdx.x, h = blockIdx.y, b = blockIdx.z;
  const int tid = threadIdx.x;
  const int wave = tid >> 6, lane = tid & 63, quad = lane >> 4, l16 = lane & 15;
  const int qbase = qt * 64;
  const size_t brow = (size_t)b * S_;

  const __hip_bfloat16* Qp = QKV + (size_t)h * 64;
  const __hip_bfloat16* Kp = Qp + 1024;
  const __hip_bfloat16* Vp = Qp + 2048;

  const int sr = tid >> 2;         // 0..63 staging row
  const int sc = (tid & 3) * 8;    // staging elem offset (16B); +32 for hi half

  // Q tile: 64 rows x 64 cols, two 16B loads per thread
  {
    const __hip_bfloat16* gq = Qp + (brow + qbase + sr) * 3072 + sc;
    *(uint4*)(&sQ[sr * 72 + sc])      = *(const uint4*)(gq);
    *(uint4*)(&sQ[sr * 72 + sc + 32]) = *(const uint4*)(gq + 32);
  }
  __syncthreads();

  // Q fragments for this wave's 16 rows (A-operand: m=lane&15, k=quad*8+j)
  bf16x8 qf0 = *(const bf16x8*)(&sQ[(wave * 16 + l16) * 72 + quad * 8]);
  bf16x8 qf1 = *(const bf16x8*)(&sQ[(wave * 16 + l16) * 72 + 32 + quad * 8]);

  float mstate[4] = {-1e30f, -1e30f, -1e30f, -1e30f};
  float lstate[4] = {0.f, 0.f, 0.f, 0.f};
  f32x4 oacc[4] = {};  // [hd-tile]; reg r = output row quad*4+r

  const __hip_bfloat16* gK = Kp + (brow + sr) * 3072 + sc;
  const __hip_bfloat16* gV = Vp + (brow + sr) * 3072 + sc;
  const int* mbase = mask + ((size_t)b * S_ + qbase + wave * 16 + quad * 4) * S_;

  for (int kt = 0; kt < S_ / 64; ++kt) {
    const int kbase = kt * 64;
    {
      const __hip_bfloat16* gk = gK + (size_t)kbase * 3072;
      *(uint4*)(&sK[sr * 72 + sc])      = *(const uint4*)(gk);
      *(uint4*)(&sK[sr * 72 + sc + 32]) = *(const uint4*)(gk + 32);
    }
    {
      const __hip_bfloat16* gv = gV + (size_t)kbase * 3072;
      union { uint4 u; __hip_bfloat16 hh[8]; } v0, v1;
      v0.u = *(const uint4*)(gv);
      v1.u = *(const uint4*)(gv + 32);
#pragma unroll
      for (int j = 0; j < 8; ++j) sVt[(sc + j) * 72 + sr]      = v0.hh[j];
#pragma unroll
      for (int j = 0; j < 8; ++j) sVt[(sc + 32 + j) * 72 + sr] = v1.hh[j];
    }
    __syncthreads();

    // scores: S = Q(16x64) @ K^T -> 4 n-tiles, k chained over 2 MFMAs
    f32x4 s[4];
#pragma unroll
    for (int nt = 0; nt < 4; ++nt) {
      bf16x8 kf0 = *(const bf16x8*)(&sK[(nt * 16 + l16) * 72 + quad * 8]);
      bf16x8 kf1 = *(const bf16x8*)(&sK[(nt * 16 + l16) * 72 + 32 + quad * 8]);
      f32x4 a = {};
      a = __builtin_amdgcn_mfma_f32_16x16x32_bf16(qf0, kf0, a, 0, 0, 0);
      a = __builtin_amdgcn_mfma_f32_16x16x32_bf16(qf1, kf1, a, 0, 0, 0);
      s[nt] = a;
    }
    // scale + mask (mask==0 -> -1e30 sentinel)
    const int* mrow = mbase + kbase;
#pragma unroll
    for (int r = 0; r < 4; ++r) {
#pragma unroll
      for (int nt = 0; nt < 4; ++nt) {
        const int mk = mrow[(size_t)r * S_ + nt * 16 + l16];
        const float sv = s[nt][r] * 0.125f;
        s[nt][r] = (mk == 0) ? -1e30f : sv;
      }
    }
    // online softmax (row-wise over 16 lanes of the quad x 4 n-tiles)
#pragma unroll
    for (int r = 0; r < 4; ++r) {
      float mx = fmaxf(fmaxf(s[0][r], s[1][r]), fmaxf(s[2][r], s[3][r]));
      mx = fmaxf(mx, __shfl_xor(mx, 1));
      mx = fmaxf(mx, __shfl_xor(mx, 2));
      mx = fmaxf(mx, __shfl_xor(mx, 4));
      mx = fmaxf(mx, __shfl_xor(mx, 8));
      const float mnew = fmaxf(mstate[r], mx);
      const float alpha = __expf(mstate[r] - mnew);
      mstate[r] = mnew;
      float sum = 0.f;
#pragma unroll
      for (int nt = 0; nt < 4; ++nt) {
        const float p = (s[nt][r] < -1e29f) ? 0.f : __expf(s[nt][r] - mnew);
        s[nt][r] = p;
        sum += p;
      }
      sum += __shfl_xor(sum, 1);
      sum += __shfl_xor(sum, 2);
      sum += __shfl_xor(sum, 4);
      sum += __shfl_xor(sum, 8);
      lstate[r] = lstate[r] * alpha + sum;
#pragma unroll
      for (int ht = 0; ht < 4; ++ht) oacc[ht][r] *= alpha;
    }
    // P: C-layout -> LDS -> A-layout
#pragma unroll
    for (int nt = 0; nt < 4; ++nt)
#pragma unroll
      for (int r = 0; r < 4; ++r)
        sP[wave][(quad * 4 + r) * 72 + nt * 16 + l16] = (__hip_bfloat16)s[nt][r];

    bf16x8 pf0 = *(const bf16x8*)(&sP[wave][l16 * 72 + quad * 8]);
    bf16x8 pf1 = *(const bf16x8*)(&sP[wave][l16 * 72 + 32 + quad * 8]);
#pragma unroll
    for (int ht = 0; ht < 4; ++ht) {
      bf16x8 vf0 = *(const bf16x8*)(&sVt[(ht * 16 + l16) * 72 + quad * 8]);
      bf16x8 vf1 = *(const bf16x8*)(&sVt[(ht * 16 + l16) * 72 + 32 + quad * 8]);
      oacc[ht] = __builtin_amdgcn_mfma_f32_16x16x32_bf16(pf0, vf0, oacc[ht], 0, 0, 0);
      oacc[ht] = __builtin_amdgcn_mfma_f32_16x16x32_bf16(pf1, vf1, oacc[ht], 0, 0, 0);
    }
    __syncthreads();  // protect sK/sVt before next tile's staging
  }

  const int orow = qbase + wave * 16 + quad * 4;
#pragma unroll
  for (int r = 0; r < 4; ++r) {
    const float inv = (lstate[r] > 0.f) ? 1.f / lstate[r] : 0.f;
#pragma unroll
    for (int ht = 0; ht < 4; ++ht)
      O[(brow + orow + r) * 1024 + h * 64 + ht * 16 + l16] =
          (__hip_bfloat16)(oacc[ht][r] * inv);
  }
}

// ---------------------------------------------------------------------------
extern "C" void kernel_launch(void* const* d_in, const int* in_sizes, int n_in,
                              void* d_out, int out_size, void* d_ws, size_t ws_size,
                              hipStream_t stream) {
  const float* x  = (const float*)d_in[0];
  const int*   mk = (const int*)d_in[1];
  const float* Wq = (const float*)d_in[2];
  const float* bq = (const float*)d_in[3];
  const float* Wk = (const float*)d_in[4];
  const float* bk = (const float*)d_in[5];
  const float* Wv = (const float*)d_in[6];
  const float* bv = (const float*)d_in[7];
  const float* Wo = (const float*)d_in[8];
  const float* bo = (const float*)d_in[9];
  float* out = (float*)d_out;

  __hip_bfloat16* X16    = (__hip_bfloat16*)d_ws;                  // [8192][1024]
  __hip_bfloat16* Wt_qkv = X16 + (size_t)B_ * S_ * D_;             // [3072][1024]
  __hip_bfloat16* Wt_o   = Wt_qkv + (size_t)3 * D_ * D_;           // [1024][1024]
  __hip_bfloat16* QKV    = Wt_o + (size_t)D_ * D_;                 // [8192][3072]
  __hip_bfloat16* Obuf   = QKV + (size_t)B_ * S_ * 3 * D_;         // [8192][1024]

  const int nx = B_ * S_ * D_;
  cvt_x<<<dim3((nx / 4 + 255) / 256), 256, 0, stream>>>(x, X16, nx);
  transpose_w<<<dim3(32, 32, 4), dim3(32, 32), 0, stream>>>(Wq, Wk, Wv, Wo, Wt_qkv, Wt_o);
  gemm_bt_bias<__hip_bfloat16><<<dim3(3 * D_ / 128, B_ * S_ / 128), 256, 0, stream>>>(
      X16, Wt_qkv, bq, bk, bv, QKV, B_ * S_, 3 * D_, D_);
  flash_attn<<<dim3(S_ / 64, H_, B_), 256, 0, stream>>>(QKV, mk, Obuf);
  gemm_bt_bias<float><<<dim3(D_ / 128, B_ * S_ / 128), 256, 0, stream>>>(
      Obuf, Wt_o, bo, bo, bo, out, B_ * S_, D_, D_);
}